// Round 1
// baseline (706.043 us; speedup 1.0000x reference)
//
#include <hip/hip_runtime.h>

#define BATCH 4096
#define SEQ   80
#define EMBED 100
#define UNITS 64
#define NPAIR (BATCH * SEQ)

__device__ __forceinline__ float fast_tanh(float x) {
    // tanh(x) = sign(x) * (1 - 2/(e^{2|x|}+1)); overflow-safe (e->inf => 1)
    float ax = fabsf(x);
    float e  = __expf(2.0f * ax);
    float r  = __builtin_amdgcn_rcpf(e + 1.0f);
    float t  = 1.0f - 2.0f * r;
    return x < 0.0f ? -t : t;
}

// ---------------------------------------------------------------------------
// Kernel 1: xw1[t][b][u] = b1[u] + sum_e emb[tokens[b][t]][e] * W1[e][u]
// One wave per (b,t) pair (strided). Lane = unit. W1 column in VGPRs.
// ---------------------------------------------------------------------------
__global__ __launch_bounds__(256, 2) void proj_kernel(
    const int*   __restrict__ tokens,
    const float* __restrict__ emb,
    const float* __restrict__ W1,
    const float* __restrict__ b1,
    float*       __restrict__ xw1)
{
    const int lane = threadIdx.x & 63;
    const int wid  = threadIdx.x >> 6;
    const int gw   = blockIdx.x * 4 + wid;
    const int GW   = gridDim.x * 4;

    float w1c[EMBED];
    #pragma unroll
    for (int e = 0; e < EMBED; ++e) w1c[e] = W1[e * UNITS + lane];
    const float b1v = b1[lane];

    for (int p = gw; p < NPAIR; p += GW) {
        const int b = p / SEQ;
        const int t = p - b * SEQ;
        const int tok = __builtin_amdgcn_readfirstlane(tokens[p]);
        const float4* row4 = reinterpret_cast<const float4*>(emb + (size_t)tok * EMBED);
        float a0 = 0.f, a1 = 0.f, a2 = 0.f, a3 = 0.f;
        #pragma unroll
        for (int e4 = 0; e4 < EMBED / 4; ++e4) {
            float4 xv = row4[e4];
            a0 += xv.x * w1c[4 * e4 + 0];
            a1 += xv.y * w1c[4 * e4 + 1];
            a2 += xv.z * w1c[4 * e4 + 2];
            a3 += xv.w * w1c[4 * e4 + 3];
        }
        const float acc = ((a0 + a1) + (a2 + a3)) + b1v;
        xw1[((size_t)t * BATCH + b) * UNITS + lane] = acc;
    }
}

// ---------------------------------------------------------------------------
// Kernel 2: the 80-step scan. 4 waves/block, each wave owns 4 batch rows.
// Lane = unit. U1/W2/U2 columns in registers; h1/h2 exchanged via LDS
// broadcasts. Waves are slot-disjoint: NO __syncthreads anywhere.
// ---------------------------------------------------------------------------
__global__ __launch_bounds__(256, 1) void rnn_kernel(
    const float* __restrict__ xw1,
    const float* __restrict__ U1,
    const float* __restrict__ W2,
    const float* __restrict__ U2,
    const float* __restrict__ b2,
    const float* __restrict__ Wo,
    const float* __restrict__ bo,
    float*       __restrict__ out)
{
    __shared__ float h1s[16][UNITS];
    __shared__ float h2s[16][UNITS];

    const int lane  = threadIdx.x & 63;
    const int wid   = threadIdx.x >> 6;
    const int slot0 = wid * 4;
    const int row0  = (blockIdx.x * 4 + wid) * 4;   // 4 consecutive batch rows

    // Recurrent matrix columns in registers (lane u holds column u).
    float u1c[UNITS], w2c[UNITS], u2c[UNITS];
    #pragma unroll
    for (int k = 0; k < UNITS; ++k) {
        u1c[k] = U1[k * UNITS + lane];
        w2c[k] = W2[k * UNITS + lane];
        u2c[k] = U2[k * UNITS + lane];
    }
    const float b2v = b2[lane];
    const float wov = Wo[lane];
    const float bov = bo[0];

    // h0 = 0
    #pragma unroll
    for (int r = 0; r < 4; ++r) {
        h1s[slot0 + r][lane] = 0.f;
        h2s[slot0 + r][lane] = 0.f;
    }
    asm volatile("s_waitcnt lgkmcnt(0)" ::: "memory");

    const float4* h1p0 = reinterpret_cast<const float4*>(&h1s[slot0 + 0][0]);
    const float4* h1p1 = reinterpret_cast<const float4*>(&h1s[slot0 + 1][0]);
    const float4* h1p2 = reinterpret_cast<const float4*>(&h1s[slot0 + 2][0]);
    const float4* h1p3 = reinterpret_cast<const float4*>(&h1s[slot0 + 3][0]);
    const float4* h2p0 = reinterpret_cast<const float4*>(&h2s[slot0 + 0][0]);
    const float4* h2p1 = reinterpret_cast<const float4*>(&h2s[slot0 + 1][0]);
    const float4* h2p2 = reinterpret_cast<const float4*>(&h2s[slot0 + 2][0]);
    const float4* h2p3 = reinterpret_cast<const float4*>(&h2s[slot0 + 3][0]);

    // prefetch xw1 for t=0
    const float* xb0 = xw1 + ((size_t)0 * BATCH + row0) * UNITS + lane;
    float xwc0 = xb0[0 * UNITS];
    float xwc1 = xb0[1 * UNITS];
    float xwc2 = xb0[2 * UNITS];
    float xwc3 = xb0[3 * UNITS];

    float c0 = 0.f, c1 = 0.f, c2 = 0.f, c3 = 0.f;   // h2 (last step survives loop)

    for (int t = 0; t < SEQ; ++t) {
        // prefetch next step's input projection
        float xwn0 = 0.f, xwn1 = 0.f, xwn2 = 0.f, xwn3 = 0.f;
        if (t < SEQ - 1) {
            const float* xb = xw1 + ((size_t)(t + 1) * BATCH + row0) * UNITS + lane;
            xwn0 = xb[0 * UNITS];
            xwn1 = xb[1 * UNITS];
            xwn2 = xb[2 * UNITS];
            xwn3 = xb[3 * UNITS];
        }

        // ---- layer 1: a[r] = xw[r] + h1_old[r] @ U1 ----
        float a0 = xwc0, a1 = xwc1, a2 = xwc2, a3 = xwc3;
        #pragma unroll
        for (int k4 = 0; k4 < UNITS / 4; ++k4) {
            float4 v0 = h1p0[k4];
            float4 v1 = h1p1[k4];
            float4 v2 = h1p2[k4];
            float4 v3 = h1p3[k4];
            a0 += v0.x * u1c[4*k4+0]; a0 += v0.y * u1c[4*k4+1]; a0 += v0.z * u1c[4*k4+2]; a0 += v0.w * u1c[4*k4+3];
            a1 += v1.x * u1c[4*k4+0]; a1 += v1.y * u1c[4*k4+1]; a1 += v1.z * u1c[4*k4+2]; a1 += v1.w * u1c[4*k4+3];
            a2 += v2.x * u1c[4*k4+0]; a2 += v2.y * u1c[4*k4+1]; a2 += v2.z * u1c[4*k4+2]; a2 += v2.w * u1c[4*k4+3];
            a3 += v3.x * u1c[4*k4+0]; a3 += v3.y * u1c[4*k4+1]; a3 += v3.z * u1c[4*k4+2]; a3 += v3.w * u1c[4*k4+3];
        }
        a0 = fast_tanh(a0);
        a1 = fast_tanh(a1);
        a2 = fast_tanh(a2);
        a3 = fast_tanh(a3);
        // publish new h1 (in-wave LDS ordering only; reads of old h1 already issued)
        h1s[slot0 + 0][lane] = a0;
        h1s[slot0 + 1][lane] = a1;
        h1s[slot0 + 2][lane] = a2;
        h1s[slot0 + 3][lane] = a3;
        asm volatile("s_waitcnt lgkmcnt(0)" ::: "memory");

        // ---- layer 2: c[r] = b2 + h1_new[r] @ W2 + h2_old[r] @ U2 ----
        c0 = b2v; c1 = b2v; c2 = b2v; c3 = b2v;
        #pragma unroll
        for (int k4 = 0; k4 < UNITS / 4; ++k4) {
            float4 x0 = h1p0[k4];
            float4 x1 = h1p1[k4];
            float4 x2 = h1p2[k4];
            float4 x3 = h1p3[k4];
            float4 y0 = h2p0[k4];
            float4 y1 = h2p1[k4];
            float4 y2 = h2p2[k4];
            float4 y3 = h2p3[k4];
            c0 += x0.x * w2c[4*k4+0]; c0 += x0.y * w2c[4*k4+1]; c0 += x0.z * w2c[4*k4+2]; c0 += x0.w * w2c[4*k4+3];
            c1 += x1.x * w2c[4*k4+0]; c1 += x1.y * w2c[4*k4+1]; c1 += x1.z * w2c[4*k4+2]; c1 += x1.w * w2c[4*k4+3];
            c2 += x2.x * w2c[4*k4+0]; c2 += x2.y * w2c[4*k4+1]; c2 += x2.z * w2c[4*k4+2]; c2 += x2.w * w2c[4*k4+3];
            c3 += x3.x * w2c[4*k4+0]; c3 += x3.y * w2c[4*k4+1]; c3 += x3.z * w2c[4*k4+2]; c3 += x3.w * w2c[4*k4+3];
            c0 += y0.x * u2c[4*k4+0]; c0 += y0.y * u2c[4*k4+1]; c0 += y0.z * u2c[4*k4+2]; c0 += y0.w * u2c[4*k4+3];
            c1 += y1.x * u2c[4*k4+0]; c1 += y1.y * u2c[4*k4+1]; c1 += y1.z * u2c[4*k4+2]; c1 += y1.w * u2c[4*k4+3];
            c2 += y2.x * u2c[4*k4+0]; c2 += y2.y * u2c[4*k4+1]; c2 += y2.z * u2c[4*k4+2]; c2 += y2.w * u2c[4*k4+3];
            c3 += y3.x * u2c[4*k4+0]; c3 += y3.y * u2c[4*k4+1]; c3 += y3.z * u2c[4*k4+2]; c3 += y3.w * u2c[4*k4+3];
        }
        c0 = fast_tanh(c0);
        c1 = fast_tanh(c1);
        c2 = fast_tanh(c2);
        c3 = fast_tanh(c3);
        h2s[slot0 + 0][lane] = c0;
        h2s[slot0 + 1][lane] = c1;
        h2s[slot0 + 2][lane] = c2;
        h2s[slot0 + 3][lane] = c3;
        asm volatile("s_waitcnt lgkmcnt(0)" ::: "memory");

        xwc0 = xwn0; xwc1 = xwn1; xwc2 = xwn2; xwc3 = xwn3;
    }

    // ---- head: out[b] = sigmoid(h2 @ Wo + bo) ----
    float pr[4] = { c0 * wov, c1 * wov, c2 * wov, c3 * wov };
    #pragma unroll
    for (int r = 0; r < 4; ++r) {
        float p = pr[r];
        #pragma unroll
        for (int off = 32; off > 0; off >>= 1) p += __shfl_xor(p, off, 64);
        if (lane == 0) {
            const float z = p + bov;
            out[row0 + r] = 1.0f / (1.0f + __expf(-z));
        }
    }
}

extern "C" void kernel_launch(void* const* d_in, const int* in_sizes, int n_in,
                              void* d_out, int out_size, void* d_ws, size_t ws_size,
                              hipStream_t stream) {
    const int*   tokens = (const int*)  d_in[0];
    const float* emb    = (const float*)d_in[1];
    const float* W1     = (const float*)d_in[2];
    const float* U1     = (const float*)d_in[3];
    const float* b1     = (const float*)d_in[4];
    const float* W2     = (const float*)d_in[5];
    const float* U2     = (const float*)d_in[6];
    const float* b2     = (const float*)d_in[7];
    const float* Wo     = (const float*)d_in[8];
    const float* bo     = (const float*)d_in[9];
    float* out = (float*)d_out;
    float* xw1 = (float*)d_ws;   // [SEQ][BATCH][UNITS] f32 = 80 MB

    proj_kernel<<<512, 256, 0, stream>>>(tokens, emb, W1, b1, xw1);
    rnn_kernel<<<256, 256, 0, stream>>>(xw1, U1, W2, U2, b2, Wo, bo, out);
}

// Round 2
// 131.883 us; speedup vs baseline: 5.3535x; 5.3535x over previous
//
#include <hip/hip_runtime.h>

#define BATCH 4096
#define SEQ   80
#define EMBED 100
#define UNITS 64
#define NWG   (BATCH / 16)     // 256 wave-groups of 16 batch rows
#define NTASK (SEQ * NWG)      // 20480 (t, wg) tasks

typedef float f32x4  __attribute__((ext_vector_type(4)));
typedef short bf16x8 __attribute__((ext_vector_type(8)));

#define MFMA16 __builtin_amdgcn_mfma_f32_16x16x32_bf16

__device__ __forceinline__ unsigned f2bfu(float f) {
    union { float f; unsigned u; } x; x.f = f;
    return (x.u + 0x7fffu + ((x.u >> 16) & 1u)) >> 16;   // RNE
}
__device__ __forceinline__ short f2bf(float f) { return (short)f2bfu(f); }
__device__ __forceinline__ unsigned pk2(float lo, float hi) {
    return f2bfu(lo) | (f2bfu(hi) << 16);
}
__device__ __forceinline__ float bflo(unsigned u) {
    union { unsigned u; float f; } x; x.u = u << 16; return x.f;
}
__device__ __forceinline__ float bfhi(unsigned u) {
    union { unsigned u; float f; } x; x.u = u & 0xffff0000u; return x.f;
}
__device__ __forceinline__ float fast_tanh(float x) {
    float ax = fabsf(x);
    float e  = __expf(2.0f * ax);
    float r  = __builtin_amdgcn_rcpf(e + 1.0f);
    float t  = 1.0f - 2.0f * r;
    return copysignf(t, x);
}

// ---------------------------------------------------------------------------
// Kernel 1 (proj): xw[t][wg] tile = b1 + emb[tokens] @ W1, written as bf16 in
// the scan's C-fragment order. D[m=unit][n=batch], A = W1^T (K=100 pad 128),
// B = gathered emb rows. One wave = one (t, wg) task (16 batch rows).
// ---------------------------------------------------------------------------
__global__ __launch_bounds__(256) void proj_kernel(
    const int*   __restrict__ tokens,
    const float* __restrict__ emb,
    const float* __restrict__ W1,
    const float* __restrict__ b1,
    uint4*       __restrict__ xw)
{
    const int lane = threadIdx.x & 63;
    const int wid  = threadIdx.x >> 6;
    const int mrow = lane & 15;
    const int kgrp = lane >> 4;

    // A-fragments of W1^T: A[m=unit][k=e] = W1[e][unit]; zero-pad e >= 100.
    bf16x8 aW1[4][4];
    #pragma unroll
    for (int mt = 0; mt < 4; ++mt)
        #pragma unroll
        for (int ks = 0; ks < 4; ++ks)
            #pragma unroll
            for (int j = 0; j < 8; ++j) {
                int e = kgrp * 8 + j + 32 * ks;
                aW1[mt][ks][j] = (e < EMBED) ? f2bf(W1[e * UNITS + mrow + 16 * mt])
                                             : (short)0;
            }
    f32x4 b1c[4];
    #pragma unroll
    for (int mt = 0; mt < 4; ++mt)
        b1c[mt] = *(const f32x4*)(b1 + 16 * mt + 4 * kgrp);

    for (int task = blockIdx.x * 4 + wid; task < NTASK; task += gridDim.x * 4) {
        const int t  = task >> 8;        // NWG == 256
        const int wg = task & 255;
        const int b  = wg * 16 + mrow;
        const int tok = tokens[b * SEQ + t];
        const float* rp = emb + (size_t)tok * EMBED;

        // B-fragments: B[k=e][n=batch] = emb[tok(b)][e]
        bf16x8 bf[4];
        #pragma unroll
        for (int ks = 0; ks < 3; ++ks) {
            f32x4 e0 = *(const f32x4*)(rp + kgrp * 8 + 32 * ks);
            f32x4 e1 = *(const f32x4*)(rp + kgrp * 8 + 32 * ks + 4);
            bf[ks][0] = f2bf(e0.x); bf[ks][1] = f2bf(e0.y);
            bf[ks][2] = f2bf(e0.z); bf[ks][3] = f2bf(e0.w);
            bf[ks][4] = f2bf(e1.x); bf[ks][5] = f2bf(e1.y);
            bf[ks][6] = f2bf(e1.z); bf[ks][7] = f2bf(e1.w);
        }
        {   // ks = 3: only e = 96..99 valid (kgrp 0, j < 4)
            bf16x8 z;
            #pragma unroll
            for (int j = 0; j < 8; ++j) z[j] = 0;
            if (kgrp == 0) {
                f32x4 e0 = *(const f32x4*)(rp + 96);
                z[0] = f2bf(e0.x); z[1] = f2bf(e0.y);
                z[2] = f2bf(e0.z); z[3] = f2bf(e0.w);
            }
            bf[3] = z;
        }

        f32x4 acc[4];
        #pragma unroll
        for (int mt = 0; mt < 4; ++mt) acc[mt] = b1c[mt];
        #pragma unroll
        for (int ks = 0; ks < 4; ++ks)
            #pragma unroll
            for (int mt = 0; mt < 4; ++mt)
                acc[mt] = MFMA16(aW1[mt][ks], bf[ks], acc[mt], 0, 0, 0);

        // pack to bf16 pairs in C-fragment order, 2 coalesced dwordx4 stores
        uint4 h0, h1;
        h0.x = pk2(acc[0][0], acc[0][1]); h0.y = pk2(acc[0][2], acc[0][3]);
        h0.z = pk2(acc[1][0], acc[1][1]); h0.w = pk2(acc[1][2], acc[1][3]);
        h1.x = pk2(acc[2][0], acc[2][1]); h1.y = pk2(acc[2][2], acc[2][3]);
        h1.z = pk2(acc[3][0], acc[3][1]); h1.w = pk2(acc[3][2], acc[3][3]);
        xw[(size_t)task * 128 + lane]      = h0;
        xw[(size_t)task * 128 + 64 + lane] = h1;
    }
}

// ---------------------------------------------------------------------------
// Kernel 2 (scan): 80-step recurrence, 1 wave per 16 batch rows.
// Transposed recurrence: D[m=unit][n=batch]; weights-as-A live in registers
// the whole scan; h1/h2 bounce through XOR-swizzled LDS [batch][unit] bf16.
// 24 MFMA / step. No cross-wave sync (64-thread blocks).
// ---------------------------------------------------------------------------
__global__ __launch_bounds__(64) void rnn_kernel(
    const uint4* __restrict__ xw,
    const float* __restrict__ U1,
    const float* __restrict__ W2,
    const float* __restrict__ U2,
    const float* __restrict__ b2,
    const float* __restrict__ Wo,
    const float* __restrict__ bo,
    float*       __restrict__ out)
{
    __shared__ __align__(16) char h1b[2048];   // [16 batch][64 unit] bf16, swizzled
    __shared__ __align__(16) char h2b[2048];

    const int lane = threadIdx.x;
    const int wg   = blockIdx.x;
    const int mrow = lane & 15;
    const int kgrp = lane >> 4;
    const int swz  = (mrow & 7) << 4;

    // zero initial state (in-wave LDS ordering is program order)
    uint4 z4 = {0u, 0u, 0u, 0u};
    ((uint4*)h1b)[lane] = z4; ((uint4*)h1b)[lane + 64] = z4;
    ((uint4*)h2b)[lane] = z4; ((uint4*)h2b)[lane + 64] = z4;

    // weight A-fragments: A[m][k] = M[k][m] (transposed recurrence)
    bf16x8 aU1[4][2], aW2[4][2], aU2[4][2];
    #pragma unroll
    for (int mt = 0; mt < 4; ++mt)
        #pragma unroll
        for (int ks = 0; ks < 2; ++ks)
            #pragma unroll
            for (int j = 0; j < 8; ++j) {
                int k = kgrp * 8 + j + 32 * ks;
                int m = mrow + 16 * mt;
                aU1[mt][ks][j] = f2bf(U1[k * UNITS + m]);
                aW2[mt][ks][j] = f2bf(W2[k * UNITS + m]);
                aU2[mt][ks][j] = f2bf(U2[k * UNITS + m]);
            }
    f32x4 b2c[4];
    #pragma unroll
    for (int mt = 0; mt < 4; ++mt)
        b2c[mt] = *(const f32x4*)(b2 + 16 * mt + 4 * kgrp);

    // prefetch xw for t=0
    uint4 xa = xw[(size_t)wg * 128 + lane];
    uint4 xb = xw[(size_t)wg * 128 + 64 + lane];

    f32x4 d2[4];
    for (int t = 0; t < SEQ; ++t) {
        uint4 na = xa, nb = xb;
        if (t < SEQ - 1) {
            size_t nbase = ((size_t)(t + 1) * NWG + wg) * 128;
            na = xw[nbase + lane];
            nb = xw[nbase + 64 + lane];
        }

        // B-fragments of previous h1, h2
        bf16x8 bh1[2], bh2[2];
        #pragma unroll
        for (int ks = 0; ks < 2; ++ks) {
            int off = (kgrp * 16 + 64 * ks) ^ swz;
            bh1[ks] = *(const bf16x8*)(h1b + mrow * 128 + off);
            bh2[ks] = *(const bf16x8*)(h2b + mrow * 128 + off);
        }

        // ---- layer 1: D1 = U1^T @ h1_old + xw (C-init from packed bf16) ----
        f32x4 d1[4];
        d1[0] = {bflo(xa.x), bfhi(xa.x), bflo(xa.y), bfhi(xa.y)};
        d1[1] = {bflo(xa.z), bfhi(xa.z), bflo(xa.w), bfhi(xa.w)};
        d1[2] = {bflo(xb.x), bfhi(xb.x), bflo(xb.y), bfhi(xb.y)};
        d1[3] = {bflo(xb.z), bfhi(xb.z), bflo(xb.w), bfhi(xb.w)};
        #pragma unroll
        for (int mt = 0; mt < 4; ++mt) {
            d1[mt] = MFMA16(aU1[mt][0], bh1[0], d1[mt], 0, 0, 0);
            d1[mt] = MFMA16(aU1[mt][1], bh1[1], d1[mt], 0, 0, 0);
        }
        #pragma unroll
        for (int mt = 0; mt < 4; ++mt)
            #pragma unroll
            for (int r = 0; r < 4; ++r) d1[mt][r] = fast_tanh(d1[mt][r]);

        // publish new h1 (write-after-read, in-order LDS)
        #pragma unroll
        for (int mt = 0; mt < 4; ++mt) {
            uint2 w;
            w.x = pk2(d1[mt][0], d1[mt][1]);
            w.y = pk2(d1[mt][2], d1[mt][3]);
            *(uint2*)(h1b + mrow * 128 + ((32 * mt + 8 * kgrp) ^ swz)) = w;
        }
        // re-read as B-fragments (compiler inserts lgkmcnt for the RAW dep)
        bf16x8 bn1[2];
        #pragma unroll
        for (int ks = 0; ks < 2; ++ks)
            bn1[ks] = *(const bf16x8*)(h1b + mrow * 128 + ((kgrp * 16 + 64 * ks) ^ swz));

        // ---- layer 2: D2 = W2^T @ h1_new + U2^T @ h2_old + b2 ----
        #pragma unroll
        for (int mt = 0; mt < 4; ++mt) {
            d2[mt] = b2c[mt];
            d2[mt] = MFMA16(aW2[mt][0], bn1[0], d2[mt], 0, 0, 0);
            d2[mt] = MFMA16(aW2[mt][1], bn1[1], d2[mt], 0, 0, 0);
            d2[mt] = MFMA16(aU2[mt][0], bh2[0], d2[mt], 0, 0, 0);
            d2[mt] = MFMA16(aU2[mt][1], bh2[1], d2[mt], 0, 0, 0);
        }
        #pragma unroll
        for (int mt = 0; mt < 4; ++mt)
            #pragma unroll
            for (int r = 0; r < 4; ++r) d2[mt][r] = fast_tanh(d2[mt][r]);

        #pragma unroll
        for (int mt = 0; mt < 4; ++mt) {
            uint2 w;
            w.x = pk2(d2[mt][0], d2[mt][1]);
            w.y = pk2(d2[mt][2], d2[mt][3]);
            *(uint2*)(h2b + mrow * 128 + ((32 * mt + 8 * kgrp) ^ swz)) = w;
        }

        xa = na; xb = nb;
    }

    // ---- head: out[b] = sigmoid(h2 @ Wo + bo) ----
    float p = 0.f;
    #pragma unroll
    for (int mt = 0; mt < 4; ++mt) {
        f32x4 w = *(const f32x4*)(Wo + 16 * mt + 4 * kgrp);
        p += d2[mt][0] * w.x + d2[mt][1] * w.y + d2[mt][2] * w.z + d2[mt][3] * w.w;
    }
    p += __shfl_xor(p, 16, 64);
    p += __shfl_xor(p, 32, 64);
    if (lane < 16) {
        float z = p + bo[0];
        out[wg * 16 + lane] = 1.0f / (1.0f + __expf(-z));
    }
}

extern "C" void kernel_launch(void* const* d_in, const int* in_sizes, int n_in,
                              void* d_out, int out_size, void* d_ws, size_t ws_size,
                              hipStream_t stream) {
    const int*   tokens = (const int*)  d_in[0];
    const float* emb    = (const float*)d_in[1];
    const float* W1     = (const float*)d_in[2];
    const float* U1     = (const float*)d_in[3];
    const float* b1     = (const float*)d_in[4];
    const float* W2     = (const float*)d_in[5];
    const float* U2     = (const float*)d_in[6];
    const float* b2     = (const float*)d_in[7];
    const float* Wo     = (const float*)d_in[8];
    const float* bo     = (const float*)d_in[9];
    float* out = (float*)d_out;
    uint4* xw  = (uint4*)d_ws;   // [NTASK][128] uint4 = 42 MB bf16 fragments

    proj_kernel<<<1280, 256, 0, stream>>>(tokens, emb, W1, b1, xw);
    rnn_kernel<<<NWG, 64, 0, stream>>>(xw, U1, W2, U2, b2, Wo, bo, out);
}

// Round 3
// 108.284 us; speedup vs baseline: 6.5203x; 1.2179x over previous
//
#include <hip/hip_runtime.h>

#define BATCH 4096
#define SEQ   80
#define EMBED 100
#define UNITS 64
#define NWG   (BATCH / 16)     // 256 wave-groups of 16 batch rows
#define NTASK (SEQ * NWG)      // 20480 (t, wg) tasks

typedef float f32x4  __attribute__((ext_vector_type(4)));
typedef short bf16x8 __attribute__((ext_vector_type(8)));

#define MFMA16 __builtin_amdgcn_mfma_f32_16x16x32_bf16

// ---- ws layout (bytes) ----
#define XW_OFF    0u            // uint4[NTASK*128]           = 41,943,040 B
#define EMB_OFF   41943040u     // ushort[10000*128]          =  2,560,000 B
#define W1T_OFF   44503040u     // ushort[64*128]             =     16,384 B
#define U1T_OFF   44519424u     // ushort[64*64]              =      8,192 B
#define W2T_OFF   44527616u
#define U2T_OFF   44535808u     // end = 44,544,000 B (~44.5 MB)

__device__ __forceinline__ unsigned f2bfu(float f) {
    union { float f; unsigned u; } x; x.f = f;
    return (x.u + 0x7fffu + ((x.u >> 16) & 1u)) >> 16;   // RNE (prep only)
}
__device__ __forceinline__ unsigned cvtpk(float lo, float hi) {
    unsigned r;
    asm("v_cvt_pk_bf16_f32 %0, %1, %2" : "=v"(r) : "v"(lo), "v"(hi));
    return r;
}
__device__ __forceinline__ float bflo(unsigned u) {
    union { unsigned u; float f; } x; x.u = u << 16; return x.f;
}
__device__ __forceinline__ float bfhi(unsigned u) {
    union { unsigned u; float f; } x; x.u = u & 0xffff0000u; return x.f;
}
__device__ __forceinline__ float fast_tanh(float x) {
    // tanh(x) = sign(x)*(1 - 2/(exp2(2*log2e*|x|)+1)); inf-safe
    float e = __builtin_amdgcn_exp2f(fabsf(x) * 2.8853900817779268f);
    float r = __builtin_amdgcn_rcpf(e + 1.0f);
    float t = __builtin_fmaf(-2.0f, r, 1.0f);
    return copysignf(t, x);
}
// permuted unit assignment: D slot (mt, row m15) <-> unit
__device__ __forceinline__ int uperm(int mt, int m15) {
    return 8 * (m15 >> 2) + 4 * (mt & 1) + (m15 & 3) + 32 * (mt >> 1);
}

// ---------------------------------------------------------------------------
// Kernel 0 (prep): bf16 tables — emb padded to K=128, transposed W1/U1/W2/U2.
// ---------------------------------------------------------------------------
__global__ __launch_bounds__(256) void prep_kernel(
    const float* __restrict__ emb, const float* __restrict__ W1,
    const float* __restrict__ U1,  const float* __restrict__ W2,
    const float* __restrict__ U2,  char* __restrict__ ws)
{
    ushort* emb_bf = (ushort*)(ws + EMB_OFF);
    ushort* w1t    = (ushort*)(ws + W1T_OFF);
    ushort* u1t    = (ushort*)(ws + U1T_OFF);
    ushort* w2t    = (ushort*)(ws + W2T_OFF);
    ushort* u2t    = (ushort*)(ws + U2T_OFF);
    const int tid    = blockIdx.x * 256 + threadIdx.x;
    const int stride = gridDim.x * 256;

    // emb: 10000 rows x 16 vec8 chunks
    for (int i = tid; i < 10000 * 16; i += stride) {
        const int r = i >> 4, kc = (i & 15) * 8;
        uint4 v;
        unsigned w[4];
        #pragma unroll
        for (int p = 0; p < 4; ++p) {
            const int k0 = kc + 2 * p;
            unsigned lo = (k0     < EMBED) ? f2bfu(emb[r * EMBED + k0])     : 0u;
            unsigned hi = (k0 + 1 < EMBED) ? f2bfu(emb[r * EMBED + k0 + 1]) : 0u;
            w[p] = lo | (hi << 16);
        }
        v.x = w[0]; v.y = w[1]; v.z = w[2]; v.w = w[3];
        *(uint4*)(emb_bf + (size_t)r * 128 + kc) = v;
    }
    // W1T[u][k], k padded to 128
    for (int i = tid; i < UNITS * 128; i += stride) {
        const int u = i >> 7, k = i & 127;
        w1t[i] = (k < EMBED) ? (ushort)f2bfu(W1[k * UNITS + u]) : (ushort)0;
    }
    // U1T/W2T/U2T [u][k] 64x64
    for (int i = tid; i < UNITS * UNITS; i += stride) {
        const int u = i >> 6, k = i & 63;
        u1t[i] = (ushort)f2bfu(U1[k * UNITS + u]);
        w2t[i] = (ushort)f2bfu(W2[k * UNITS + u]);
        u2t[i] = (ushort)f2bfu(U2[k * UNITS + u]);
    }
}

// ---------------------------------------------------------------------------
// Kernel 1 (proj): xw tile = b1 + emb[tokens] @ W1 in permuted C-frag order.
// ---------------------------------------------------------------------------
__global__ __launch_bounds__(256) void proj_kernel(
    const int*   __restrict__ tokens,
    const float* __restrict__ b1,
    char*        __restrict__ ws)
{
    const ushort* emb_bf = (const ushort*)(ws + EMB_OFF);
    const ushort* w1t    = (const ushort*)(ws + W1T_OFF);
    uint4*        xw     = (uint4*)(ws + XW_OFF);

    const int lane = threadIdx.x & 63;
    const int wid  = threadIdx.x >> 6;
    const int m15  = lane & 15;
    const int kgrp = lane >> 4;

    // A-frags of W1^T with permuted m-units
    bf16x8 aW1[4][4];
    #pragma unroll
    for (int mt = 0; mt < 4; ++mt) {
        const int u = uperm(mt, m15);
        #pragma unroll
        for (int ks = 0; ks < 4; ++ks)
            aW1[mt][ks] = *(const bf16x8*)(w1t + u * 128 + kgrp * 8 + 32 * ks);
    }
    f32x4 b1c[4];
    #pragma unroll
    for (int mt = 0; mt < 4; ++mt)
        b1c[mt] = *(const f32x4*)(b1 + 8 * kgrp + 4 * (mt & 1) + 32 * (mt >> 1));

    for (int task = blockIdx.x * 4 + wid; task < NTASK; task += gridDim.x * 4) {
        const int t  = task >> 8;          // NWG == 256
        const int wg = task & 255;
        const int b  = wg * 16 + m15;
        const int tok = tokens[b * SEQ + t];

        bf16x8 bf[4];
        #pragma unroll
        for (int ks = 0; ks < 4; ++ks)
            bf[ks] = *(const bf16x8*)(emb_bf + (size_t)tok * 128 + kgrp * 8 + 32 * ks);

        f32x4 acc[4];
        #pragma unroll
        for (int mt = 0; mt < 4; ++mt) acc[mt] = b1c[mt];
        #pragma unroll
        for (int ks = 0; ks < 4; ++ks)
            #pragma unroll
            for (int mt = 0; mt < 4; ++mt)
                acc[mt] = MFMA16(aW1[mt][ks], bf[ks], acc[mt], 0, 0, 0);

        uint4 h0, h1;
        h0.x = cvtpk(acc[0][0], acc[0][1]); h0.y = cvtpk(acc[0][2], acc[0][3]);
        h0.z = cvtpk(acc[1][0], acc[1][1]); h0.w = cvtpk(acc[1][2], acc[1][3]);
        h1.x = cvtpk(acc[2][0], acc[2][1]); h1.y = cvtpk(acc[2][2], acc[2][3]);
        h1.z = cvtpk(acc[3][0], acc[3][1]); h1.w = cvtpk(acc[3][2], acc[3][3]);
        xw[(size_t)task * 128 + lane]      = h0;
        xw[(size_t)task * 128 + 64 + lane] = h1;
    }
}

// ---------------------------------------------------------------------------
// Kernel 2 (scan): fully register-resident recurrence. No LDS, no shuffles.
// D slot (mt,reg) == B slot (mt>>1, 4*(mt&1)+reg) in the SAME lane by unit
// permutation, so h-handoff = 8 v_cvt_pk per vector.
// ---------------------------------------------------------------------------
__global__ __launch_bounds__(64) void rnn_kernel(
    const float* __restrict__ b2,
    const float* __restrict__ Wo,
    const float* __restrict__ bo,
    float*       __restrict__ out,
    const char*  __restrict__ ws)
{
    const uint4*  xw  = (const uint4*)(ws + XW_OFF);
    const ushort* u1t = (const ushort*)(ws + U1T_OFF);
    const ushort* w2t = (const ushort*)(ws + W2T_OFF);
    const ushort* u2t = (const ushort*)(ws + U2T_OFF);

    const int lane = threadIdx.x;
    const int wg   = blockIdx.x;
    const int m15  = lane & 15;
    const int kgrp = lane >> 4;

    // weight A-frags (permuted m-units, standard k-order)
    bf16x8 aU1[4][2], aW2[4][2], aU2[4][2];
    #pragma unroll
    for (int mt = 0; mt < 4; ++mt) {
        const int u = uperm(mt, m15);
        #pragma unroll
        for (int ks = 0; ks < 2; ++ks) {
            aU1[mt][ks] = *(const bf16x8*)(u1t + u * 64 + kgrp * 8 + 32 * ks);
            aW2[mt][ks] = *(const bf16x8*)(w2t + u * 64 + kgrp * 8 + 32 * ks);
            aU2[mt][ks] = *(const bf16x8*)(u2t + u * 64 + kgrp * 8 + 32 * ks);
        }
    }
    f32x4 b2c[4];
    #pragma unroll
    for (int mt = 0; mt < 4; ++mt)
        b2c[mt] = *(const f32x4*)(b2 + 8 * kgrp + 4 * (mt & 1) + 32 * (mt >> 1));

    // register-resident h-state as B-fragments
    uint4 pb1[2], pb2[2];
    pb1[0] = pb1[1] = pb2[0] = pb2[1] = uint4{0u, 0u, 0u, 0u};

    // 2-deep xw prefetch
    uint4 xa0 = xw[(size_t)wg * 128 + lane];
    uint4 xb0 = xw[(size_t)wg * 128 + 64 + lane];
    uint4 xa1 = xw[((size_t)NWG + wg) * 128 + lane];
    uint4 xb1 = xw[((size_t)NWG + wg) * 128 + 64 + lane];

    f32x4 d2[4];
    for (int t = 0; t < SEQ; ++t) {
        uint4 xa2 = xa1, xb2 = xb1;
        if (t < SEQ - 2) {
            const size_t nb = ((size_t)(t + 2) * NWG + wg) * 128;
            xa2 = xw[nb + lane];
            xb2 = xw[nb + 64 + lane];
        }

        // ---- layer 1: D1 = U1^T @ h1_old + xw ----
        f32x4 d1[4];
        d1[0] = {bflo(xa0.x), bfhi(xa0.x), bflo(xa0.y), bfhi(xa0.y)};
        d1[1] = {bflo(xa0.z), bfhi(xa0.z), bflo(xa0.w), bfhi(xa0.w)};
        d1[2] = {bflo(xb0.x), bfhi(xb0.x), bflo(xb0.y), bfhi(xb0.y)};
        d1[3] = {bflo(xb0.z), bfhi(xb0.z), bflo(xb0.w), bfhi(xb0.w)};
        #pragma unroll
        for (int mt = 0; mt < 4; ++mt) {
            d1[mt] = MFMA16(aU1[mt][0], *(const bf16x8*)&pb1[0], d1[mt], 0, 0, 0);
            d1[mt] = MFMA16(aU1[mt][1], *(const bf16x8*)&pb1[1], d1[mt], 0, 0, 0);
        }
        #pragma unroll
        for (int mt = 0; mt < 4; ++mt)
            #pragma unroll
            for (int r = 0; r < 4; ++r) d1[mt][r] = fast_tanh(d1[mt][r]);

        // in-lane repack: new h1 B-frags
        #pragma unroll
        for (int ks = 0; ks < 2; ++ks) {
            pb1[ks].x = cvtpk(d1[2 * ks][0],     d1[2 * ks][1]);
            pb1[ks].y = cvtpk(d1[2 * ks][2],     d1[2 * ks][3]);
            pb1[ks].z = cvtpk(d1[2 * ks + 1][0], d1[2 * ks + 1][1]);
            pb1[ks].w = cvtpk(d1[2 * ks + 1][2], d1[2 * ks + 1][3]);
        }

        // ---- layer 2: D2 = W2^T @ h1_new + U2^T @ h2_old + b2 ----
        #pragma unroll
        for (int mt = 0; mt < 4; ++mt) {
            d2[mt] = b2c[mt];
            d2[mt] = MFMA16(aW2[mt][0], *(const bf16x8*)&pb1[0], d2[mt], 0, 0, 0);
            d2[mt] = MFMA16(aW2[mt][1], *(const bf16x8*)&pb1[1], d2[mt], 0, 0, 0);
            d2[mt] = MFMA16(aU2[mt][0], *(const bf16x8*)&pb2[0], d2[mt], 0, 0, 0);
            d2[mt] = MFMA16(aU2[mt][1], *(const bf16x8*)&pb2[1], d2[mt], 0, 0, 0);
        }
        #pragma unroll
        for (int mt = 0; mt < 4; ++mt)
            #pragma unroll
            for (int r = 0; r < 4; ++r) d2[mt][r] = fast_tanh(d2[mt][r]);

        #pragma unroll
        for (int ks = 0; ks < 2; ++ks) {
            pb2[ks].x = cvtpk(d2[2 * ks][0],     d2[2 * ks][1]);
            pb2[ks].y = cvtpk(d2[2 * ks][2],     d2[2 * ks][3]);
            pb2[ks].z = cvtpk(d2[2 * ks + 1][0], d2[2 * ks + 1][1]);
            pb2[ks].w = cvtpk(d2[2 * ks + 1][2], d2[2 * ks + 1][3]);
        }

        xa0 = xa1; xb0 = xb1; xa1 = xa2; xb1 = xb2;
    }

    // ---- head: out[b] = sigmoid(h2 @ Wo + bo), permuted Wo gather ----
    float p = 0.f;
    #pragma unroll
    for (int mt = 0; mt < 4; ++mt) {
        f32x4 w = *(const f32x4*)(Wo + 8 * kgrp + 4 * (mt & 1) + 32 * (mt >> 1));
        p += d2[mt][0] * w.x + d2[mt][1] * w.y + d2[mt][2] * w.z + d2[mt][3] * w.w;
    }
    p += __shfl_xor(p, 16, 64);
    p += __shfl_xor(p, 32, 64);
    if (lane < 16) {
        const float z = p + bo[0];
        const float e = __builtin_amdgcn_exp2f(-z * 1.4426950408889634f);
        out[wg * 16 + lane] = __builtin_amdgcn_rcpf(1.0f + e);
    }
}

extern "C" void kernel_launch(void* const* d_in, const int* in_sizes, int n_in,
                              void* d_out, int out_size, void* d_ws, size_t ws_size,
                              hipStream_t stream) {
    const int*   tokens = (const int*)  d_in[0];
    const float* emb    = (const float*)d_in[1];
    const float* W1     = (const float*)d_in[2];
    const float* U1     = (const float*)d_in[3];
    const float* b1     = (const float*)d_in[4];
    const float* W2     = (const float*)d_in[5];
    const float* U2     = (const float*)d_in[6];
    const float* b2     = (const float*)d_in[7];
    const float* Wo     = (const float*)d_in[8];
    const float* bo     = (const float*)d_in[9];
    float* out = (float*)d_out;
    char*  ws  = (char*)d_ws;

    prep_kernel<<<640, 256, 0, stream>>>(emb, W1, U1, W2, U2, ws);
    proj_kernel<<<2560, 256, 0, stream>>>(tokens, b1, ws);
    rnn_kernel<<<NWG, 64, 0, stream>>>(b2, Wo, bo, out, ws);
}

// Round 4
// 65.458 us; speedup vs baseline: 10.7862x; 1.6542x over previous
//
#include <hip/hip_runtime.h>

#define BATCH 4096
#define SEQ   80
#define EMBED 100
#define UNITS 64
#define NWG   (BATCH / 16)     // 256 blocks, 16 batch rows each

typedef float f32x4  __attribute__((ext_vector_type(4)));
typedef short bf16x8 __attribute__((ext_vector_type(8)));

#define MFMA16 __builtin_amdgcn_mfma_f32_16x16x32_bf16

// ---- ws layout (bytes) ----
#define EMB_OFF 0u           // ushort[10000*128] = 2,560,000 B (zero-padded K)
#define W1T_OFF 2560000u     // ushort[64*128]
#define U1T_OFF 2576384u     // ushort[64*64]
#define W2T_OFF 2584576u
#define U2T_OFF 2592768u     // end ~2.6 MB

__device__ __forceinline__ unsigned f2bfu(float f) {
    union { float f; unsigned u; } x; x.f = f;
    return (x.u + 0x7fffu + ((x.u >> 16) & 1u)) >> 16;   // RNE (prep only)
}
__device__ __forceinline__ unsigned cvtpk(float lo, float hi) {
    unsigned r;
    asm("v_cvt_pk_bf16_f32 %0, %1, %2" : "=v"(r) : "v"(lo), "v"(hi));
    return r;
}
__device__ __forceinline__ float fast_tanh(float x) {
    float e = __builtin_amdgcn_exp2f(fabsf(x) * 2.8853900817779268f);
    float r = __builtin_amdgcn_rcpf(e + 1.0f);
    float t = __builtin_fmaf(-2.0f, r, 1.0f);
    return copysignf(t, x);
}

// ---------------------------------------------------------------------------
// prep: bf16 tables — emb padded to K=128, transposed W1/U1/W2/U2.
// ---------------------------------------------------------------------------
__global__ __launch_bounds__(256) void prep_kernel(
    const float* __restrict__ emb, const float* __restrict__ W1,
    const float* __restrict__ U1,  const float* __restrict__ W2,
    const float* __restrict__ U2,  char* __restrict__ ws)
{
    ushort* emb_bf = (ushort*)(ws + EMB_OFF);
    ushort* w1t    = (ushort*)(ws + W1T_OFF);
    ushort* u1t    = (ushort*)(ws + U1T_OFF);
    ushort* w2t    = (ushort*)(ws + W2T_OFF);
    ushort* u2t    = (ushort*)(ws + U2T_OFF);
    const int tid    = blockIdx.x * 256 + threadIdx.x;
    const int stride = gridDim.x * 256;

    for (int i = tid; i < 10000 * 16; i += stride) {
        const int r = i >> 4, kc = (i & 15) * 8;
        unsigned w[4];
        #pragma unroll
        for (int p = 0; p < 4; ++p) {
            const int k0 = kc + 2 * p;
            unsigned lo = (k0     < EMBED) ? f2bfu(emb[r * EMBED + k0])     : 0u;
            unsigned hi = (k0 + 1 < EMBED) ? f2bfu(emb[r * EMBED + k0 + 1]) : 0u;
            w[p] = lo | (hi << 16);
        }
        uint4 v; v.x = w[0]; v.y = w[1]; v.z = w[2]; v.w = w[3];
        *(uint4*)(emb_bf + (size_t)r * 128 + kc) = v;
    }
    for (int i = tid; i < UNITS * 128; i += stride) {
        const int u = i >> 7, k = i & 127;
        w1t[i] = (k < EMBED) ? (ushort)f2bfu(W1[k * UNITS + u]) : (ushort)0;
    }
    for (int i = tid; i < UNITS * UNITS; i += stride) {
        const int u = i >> 6, k = i & 63;
        u1t[i] = (ushort)f2bfu(U1[k * UNITS + u]);
        w2t[i] = (ushort)f2bfu(W2[k * UNITS + u]);
        u2t[i] = (ushort)f2bfu(U2[k * UNITS + u]);
    }
}

// ---------------------------------------------------------------------------
// rnn: fused proj + 80-step scan. 4 waves/block (M-split: 16 units each),
// 256 blocks -> 1024 waves = 1 wave on every SIMD of the chip.
// h1/h2 double-buffered in LDS (XOR swizzle); raw s_barrier + lgkmcnt(0)
// so emb gathers stay in flight across barriers.
// ---------------------------------------------------------------------------
__global__ __launch_bounds__(256, 1) void rnn_kernel(
    const int*   __restrict__ tokens,
    const float* __restrict__ b1,
    const float* __restrict__ b2,
    const float* __restrict__ Wo,
    const float* __restrict__ bo,
    float*       __restrict__ out,
    const char*  __restrict__ ws)
{
    __shared__ __align__(16) char h1L[2][2048];   // [batch16][unit64] bf16, swz
    __shared__ __align__(16) char h2L[2][2048];
    __shared__ float headp[4][16];

    const ushort* emb_bf = (const ushort*)(ws + EMB_OFF);
    const ushort* w1t    = (const ushort*)(ws + W1T_OFF);
    const ushort* u1t    = (const ushort*)(ws + U1T_OFF);
    const ushort* w2t    = (const ushort*)(ws + W2T_OFF);
    const ushort* u2t    = (const ushort*)(ws + U2T_OFF);

    const int lane = threadIdx.x & 63;
    const int w    = threadIdx.x >> 6;    // wave id = unit-slice id
    const int m15  = lane & 15;
    const int kgrp = lane >> 4;
    const int swz  = (m15 & 7) << 4;
    const int wg   = blockIdx.x;
    const long b80 = (long)(wg * 16 + m15) * SEQ;

    // zero initial state buffers
    {
        uint4 z = {0u, 0u, 0u, 0u};
        const int tid = threadIdx.x;
        if (tid < 128) ((uint4*)h1L[0])[tid] = z;
        else           ((uint4*)h2L[0])[tid - 128] = z;
    }

    // weight A-fragments for this wave's unit slice (rows m = 16w..16w+15)
    const int urow = 16 * w + m15;
    bf16x8 aW1[4], aU1[2], aW2[2], aU2[2];
    #pragma unroll
    for (int ks = 0; ks < 4; ++ks)
        aW1[ks] = *(const bf16x8*)(w1t + urow * 128 + kgrp * 8 + 32 * ks);
    #pragma unroll
    for (int ks = 0; ks < 2; ++ks) {
        aU1[ks] = *(const bf16x8*)(u1t + urow * 64 + kgrp * 8 + 32 * ks);
        aW2[ks] = *(const bf16x8*)(w2t + urow * 64 + kgrp * 8 + 32 * ks);
        aU2[ks] = *(const bf16x8*)(u2t + urow * 64 + kgrp * 8 + 32 * ks);
    }
    const int ubase = 16 * w + 4 * kgrp;          // D-row base unit
    const f32x4 b1c = *(const f32x4*)(b1 + ubase);
    const f32x4 b2c = *(const f32x4*)(b2 + ubase);

    __syncthreads();   // h buffers zeroed (full barrier, once)

    // ---- emb prologue: tiles for t=0,1 + tokens for t=2,3 ----
    const int tk0 = tokens[b80 + 0];
    const int tk1 = tokens[b80 + 1];
    bf16x8 eA0, eA1, eA2, eA3, eB0, eB1, eB2, eB3;
    {
        const ushort* er = emb_bf + (size_t)tk0 * 128 + kgrp * 8;
        eA0 = *(const bf16x8*)(er);      eA1 = *(const bf16x8*)(er + 32);
        eA2 = *(const bf16x8*)(er + 64); eA3 = *(const bf16x8*)(er + 96);
    }
    {
        const ushort* er = emb_bf + (size_t)tk1 * 128 + kgrp * 8;
        eB0 = *(const bf16x8*)(er);      eB1 = *(const bf16x8*)(er + 32);
        eB2 = *(const bf16x8*)(er + 64); eB3 = *(const bf16x8*)(er + 96);
    }
    int tokA = tokens[b80 + 2];
    int tokB = tokens[b80 + 3];

    float d2f0 = 0.f, d2f1 = 0.f, d2f2 = 0.f, d2f3 = 0.f;

// one timestep: read h[P], write h[Q]; consume+refill emb buffer E*.
// Raw barriers: wait LDS only, leave global gathers in flight.
#define LBAR() do { asm volatile("s_waitcnt lgkmcnt(0)" ::: "memory"); \
                    __builtin_amdgcn_s_barrier(); } while (0)
#define STEP(T, E0, E1, E2, E3, TOK, P, Q)                                      \
  {                                                                             \
    bf16x8 bh1a = *(const bf16x8*)(h1L[P] + m15 * 128 + ((kgrp * 16     ) ^ swz)); \
    bf16x8 bh1b = *(const bf16x8*)(h1L[P] + m15 * 128 + ((kgrp * 16 + 64) ^ swz)); \
    bf16x8 bh2a = *(const bf16x8*)(h2L[P] + m15 * 128 + ((kgrp * 16     ) ^ swz)); \
    bf16x8 bh2b = *(const bf16x8*)(h2L[P] + m15 * 128 + ((kgrp * 16 + 64) ^ swz)); \
    f32x4 dA = b1c;                                                             \
    dA = MFMA16(aW1[0], E0, dA, 0, 0, 0);                                       \
    dA = MFMA16(aW1[1], E1, dA, 0, 0, 0);                                       \
    dA = MFMA16(aW1[2], E2, dA, 0, 0, 0);                                       \
    dA = MFMA16(aW1[3], E3, dA, 0, 0, 0);                                       \
    f32x4 dB = {0.f, 0.f, 0.f, 0.f};                                            \
    dB = MFMA16(aU1[0], bh1a, dB, 0, 0, 0);                                     \
    dB = MFMA16(aU1[1], bh1b, dB, 0, 0, 0);                                     \
    /* refill this emb buffer for step T+2 (in flight across barriers) */       \
    {                                                                           \
        const ushort* er = emb_bf + (size_t)TOK * 128 + kgrp * 8;               \
        E0 = *(const bf16x8*)(er);      E1 = *(const bf16x8*)(er + 32);         \
        E2 = *(const bf16x8*)(er + 64); E3 = *(const bf16x8*)(er + 96);         \
    }                                                                           \
    TOK = tokens[b80 + ((T) + 4 < SEQ ? (T) + 4 : SEQ - 1)];                    \
    float t0 = fast_tanh(dA[0] + dB[0]);                                        \
    float t1 = fast_tanh(dA[1] + dB[1]);                                        \
    float t2 = fast_tanh(dA[2] + dB[2]);                                        \
    float t3 = fast_tanh(dA[3] + dB[3]);                                        \
    {                                                                           \
        uint2 pk; pk.x = cvtpk(t0, t1); pk.y = cvtpk(t2, t3);                   \
        *(uint2*)(h1L[Q] + m15 * 128 + ((32 * w + 8 * kgrp) ^ swz)) = pk;       \
    }                                                                           \
    LBAR();                                                                     \
    bf16x8 bn1a = *(const bf16x8*)(h1L[Q] + m15 * 128 + ((kgrp * 16     ) ^ swz)); \
    bf16x8 bn1b = *(const bf16x8*)(h1L[Q] + m15 * 128 + ((kgrp * 16 + 64) ^ swz)); \
    f32x4 dC = b2c;                                                             \
    dC = MFMA16(aW2[0], bn1a, dC, 0, 0, 0);                                     \
    dC = MFMA16(aW2[1], bn1b, dC, 0, 0, 0);                                     \
    f32x4 dD = {0.f, 0.f, 0.f, 0.f};                                            \
    dD = MFMA16(aU2[0], bh2a, dD, 0, 0, 0);                                     \
    dD = MFMA16(aU2[1], bh2b, dD, 0, 0, 0);                                     \
    d2f0 = fast_tanh(dC[0] + dD[0]);                                            \
    d2f1 = fast_tanh(dC[1] + dD[1]);                                            \
    d2f2 = fast_tanh(dC[2] + dD[2]);                                            \
    d2f3 = fast_tanh(dC[3] + dD[3]);                                            \
    {                                                                           \
        uint2 pk; pk.x = cvtpk(d2f0, d2f1); pk.y = cvtpk(d2f2, d2f3);           \
        *(uint2*)(h2L[Q] + m15 * 128 + ((32 * w + 8 * kgrp) ^ swz)) = pk;       \
    }                                                                           \
    LBAR();                                                                     \
  }

    for (int t = 0; t < SEQ; t += 2) {
        STEP(t,     eA0, eA1, eA2, eA3, tokA, 0, 1)
        STEP(t + 1, eB0, eB1, eB2, eB3, tokB, 1, 0)
    }
#undef STEP
#undef LBAR

    // ---- head: out[b] = sigmoid(h2 @ Wo + bo) ----
    const f32x4 woc = *(const f32x4*)(Wo + ubase);
    float p = d2f0 * woc[0] + d2f1 * woc[1] + d2f2 * woc[2] + d2f3 * woc[3];
    p += __shfl_xor(p, 16, 64);
    p += __shfl_xor(p, 32, 64);
    if (lane < 16) headp[w][lane] = p;
    __syncthreads();
    if (threadIdx.x < 16) {
        const float z = headp[0][threadIdx.x] + headp[1][threadIdx.x]
                      + headp[2][threadIdx.x] + headp[3][threadIdx.x] + bo[0];
        const float e = __builtin_amdgcn_exp2f(-z * 1.4426950408889634f);
        out[wg * 16 + threadIdx.x] = __builtin_amdgcn_rcpf(1.0f + e);
    }
}

extern "C" void kernel_launch(void* const* d_in, const int* in_sizes, int n_in,
                              void* d_out, int out_size, void* d_ws, size_t ws_size,
                              hipStream_t stream) {
    const int*   tokens = (const int*)  d_in[0];
    const float* emb    = (const float*)d_in[1];
    const float* W1     = (const float*)d_in[2];
    const float* U1     = (const float*)d_in[3];
    const float* b1     = (const float*)d_in[4];
    const float* W2     = (const float*)d_in[5];
    const float* U2     = (const float*)d_in[6];
    const float* b2     = (const float*)d_in[7];
    const float* Wo     = (const float*)d_in[8];
    const float* bo     = (const float*)d_in[9];
    float* out = (float*)d_out;
    char*  ws  = (char*)d_ws;

    prep_kernel<<<640, 256, 0, stream>>>(emb, W1, U1, W2, U2, ws);
    rnn_kernel<<<NWG, 256, 0, stream>>>(tokens, b1, b2, Wo, bo, out, ws);
}

// Round 5
// 61.568 us; speedup vs baseline: 11.4677x; 1.0632x over previous
//
#include <hip/hip_runtime.h>

#define BATCH 4096
#define SEQ   80
#define EMBED 100
#define UNITS 64
#define NWG   (BATCH / 16)     // 256 blocks, 16 batch rows each

typedef float f32x4  __attribute__((ext_vector_type(4)));
typedef short bf16x8 __attribute__((ext_vector_type(8)));

#define MFMA16 __builtin_amdgcn_mfma_f32_16x16x32_bf16

// ---- ws layout (bytes) ----
#define EMB_OFF 0u           // ushort[10000*128] = 2,560,000 B (zero-padded K)
#define W1T_OFF 2560000u     // ushort[64*128]
#define U1T_OFF 2576384u     // ushort[64*64]
#define W2T_OFF 2584576u
#define U2T_OFF 2592768u     // end ~2.6 MB

__device__ __forceinline__ unsigned f2bfu(float f) {
    union { float f; unsigned u; } x; x.f = f;
    return (x.u + 0x7fffu + ((x.u >> 16) & 1u)) >> 16;   // RNE (prep only)
}
__device__ __forceinline__ unsigned cvtpk(float lo, float hi) {
    unsigned r;
    asm("v_cvt_pk_bf16_f32 %0, %1, %2" : "=v"(r) : "v"(lo), "v"(hi));
    return r;
}
__device__ __forceinline__ float fast_tanh(float x) {
    float e = __builtin_amdgcn_exp2f(fabsf(x) * 2.8853900817779268f);
    float r = __builtin_amdgcn_rcpf(e + 1.0f);
    float t = __builtin_fmaf(-2.0f, r, 1.0f);
    return copysignf(t, x);
}

// ---------------------------------------------------------------------------
// prep: bf16 tables — emb padded to K=128, transposed W1/U1/W2/U2.
// ---------------------------------------------------------------------------
__global__ __launch_bounds__(256) void prep_kernel(
    const float* __restrict__ emb, const float* __restrict__ W1,
    const float* __restrict__ U1,  const float* __restrict__ W2,
    const float* __restrict__ U2,  char* __restrict__ ws)
{
    ushort* emb_bf = (ushort*)(ws + EMB_OFF);
    ushort* w1t    = (ushort*)(ws + W1T_OFF);
    ushort* u1t    = (ushort*)(ws + U1T_OFF);
    ushort* w2t    = (ushort*)(ws + W2T_OFF);
    ushort* u2t    = (ushort*)(ws + U2T_OFF);
    const int tid    = blockIdx.x * 256 + threadIdx.x;
    const int stride = gridDim.x * 256;

    for (int i = tid; i < 10000 * 16; i += stride) {
        const int r = i >> 4, kc = (i & 15) * 8;
        unsigned w[4];
        #pragma unroll
        for (int p = 0; p < 4; ++p) {
            const int k0 = kc + 2 * p;
            unsigned lo = (k0     < EMBED) ? f2bfu(emb[r * EMBED + k0])     : 0u;
            unsigned hi = (k0 + 1 < EMBED) ? f2bfu(emb[r * EMBED + k0 + 1]) : 0u;
            w[p] = lo | (hi << 16);
        }
        uint4 v; v.x = w[0]; v.y = w[1]; v.z = w[2]; v.w = w[3];
        *(uint4*)(emb_bf + (size_t)r * 128 + kc) = v;
    }
    for (int i = tid; i < UNITS * 128; i += stride) {
        const int u = i >> 7, k = i & 127;
        w1t[i] = (k < EMBED) ? (ushort)f2bfu(W1[k * UNITS + u]) : (ushort)0;
    }
    for (int i = tid; i < UNITS * UNITS; i += stride) {
        const int u = i >> 6, k = i & 63;
        u1t[i] = (ushort)f2bfu(U1[k * UNITS + u]);
        w2t[i] = (ushort)f2bfu(W2[k * UNITS + u]);
        u2t[i] = (ushort)f2bfu(U2[k * UNITS + u]);
    }
}

// ---------------------------------------------------------------------------
// rnn: fused proj + scan, ONE barrier per timestep.
// Phase t: reads {h1[t], h2[t-1]} from LDS buf P, computes
//   h2[t]   = tanh(W2 h1[t] + U2 h2[t-1] + b2)      (two split acc chains)
//   h1[t+1] = tanh(b1 + W1 emb[t+1] + U1 h1[t])     (emb MFMAs hide ds_read)
// writes both to buf Q, one lgkmcnt+barrier. 4 waves/block M-split,
// 256 blocks -> 1024 waves = every SIMD busy.
// ---------------------------------------------------------------------------
__global__ __launch_bounds__(256, 1) void rnn_kernel(
    const int*   __restrict__ tokens,
    const float* __restrict__ b1,
    const float* __restrict__ b2,
    const float* __restrict__ Wo,
    const float* __restrict__ bo,
    float*       __restrict__ out,
    const char*  __restrict__ ws)
{
    __shared__ __align__(16) char h1L[2][2048];   // [batch16][unit64] bf16, swz
    __shared__ __align__(16) char h2L[2][2048];
    __shared__ float headp[4][16];

    const ushort* emb_bf = (const ushort*)(ws + EMB_OFF);
    const ushort* w1t    = (const ushort*)(ws + W1T_OFF);
    const ushort* u1t    = (const ushort*)(ws + U1T_OFF);
    const ushort* w2t    = (const ushort*)(ws + W2T_OFF);
    const ushort* u2t    = (const ushort*)(ws + U2T_OFF);

    const int lane = threadIdx.x & 63;
    const int w    = threadIdx.x >> 6;    // wave id = unit-slice id
    const int m15  = lane & 15;
    const int kgrp = lane >> 4;
    const int swz  = (m15 & 7) << 4;
    const int wg   = blockIdx.x;
    const long b80 = (long)(wg * 16 + m15) * SEQ;

    // zero h2[-1] buffer (buf 0)
    {
        uint4 z = {0u, 0u, 0u, 0u};
        if (threadIdx.x < 128) ((uint4*)h2L[0])[threadIdx.x] = z;
    }

    // weight A-fragments for this wave's unit slice (rows m = 16w..16w+15)
    const int urow = 16 * w + m15;
    bf16x8 aW1[4], aU1[2], aW2[2], aU2[2];
    #pragma unroll
    for (int ks = 0; ks < 4; ++ks)
        aW1[ks] = *(const bf16x8*)(w1t + urow * 128 + kgrp * 8 + 32 * ks);
    #pragma unroll
    for (int ks = 0; ks < 2; ++ks) {
        aU1[ks] = *(const bf16x8*)(u1t + urow * 64 + kgrp * 8 + 32 * ks);
        aW2[ks] = *(const bf16x8*)(w2t + urow * 64 + kgrp * 8 + 32 * ks);
        aU2[ks] = *(const bf16x8*)(u2t + urow * 64 + kgrp * 8 + 32 * ks);
    }
    const int ubase = 16 * w + 4 * kgrp;          // D-row base unit
    const f32x4 b1c = *(const f32x4*)(b1 + ubase);
    const f32x4 b2c = *(const f32x4*)(b2 + ubase);

    // ---- emb prologue: tile0 -> X, tile1 -> Y; TOKX=tok2, TOKY=tok3 ----
    bf16x8 eX0, eX1, eX2, eX3, eY0, eY1, eY2, eY3;
    {
        const int tk0 = tokens[b80 + 0];
        const ushort* er = emb_bf + (size_t)tk0 * 128 + kgrp * 8;
        eX0 = *(const bf16x8*)(er);      eX1 = *(const bf16x8*)(er + 32);
        eX2 = *(const bf16x8*)(er + 64); eX3 = *(const bf16x8*)(er + 96);
    }
    {
        const int tk1 = tokens[b80 + 1];
        const ushort* er = emb_bf + (size_t)tk1 * 128 + kgrp * 8;
        eY0 = *(const bf16x8*)(er);      eY1 = *(const bf16x8*)(er + 32);
        eY2 = *(const bf16x8*)(er + 64); eY3 = *(const bf16x8*)(er + 96);
    }
    int tokX = tokens[b80 + 2];
    int tokY = tokens[b80 + 3];

    // ---- prologue phase: h1[0] = tanh(b1 + W1 emb[0]) -> buf 0 ----
    {
        f32x4 dH = b1c;
        dH = MFMA16(aW1[0], eX0, dH, 0, 0, 0);
        dH = MFMA16(aW1[1], eX1, dH, 0, 0, 0);
        dH = MFMA16(aW1[2], eX2, dH, 0, 0, 0);
        dH = MFMA16(aW1[3], eX3, dH, 0, 0, 0);
        // refill X with tile2 while tanh runs
        const ushort* er = emb_bf + (size_t)tokX * 128 + kgrp * 8;
        eX0 = *(const bf16x8*)(er);      eX1 = *(const bf16x8*)(er + 32);
        eX2 = *(const bf16x8*)(er + 64); eX3 = *(const bf16x8*)(er + 96);
        tokX = tokens[b80 + 4];
        float t0 = fast_tanh(dH[0]), t1 = fast_tanh(dH[1]);
        float t2 = fast_tanh(dH[2]), t3 = fast_tanh(dH[3]);
        uint2 pk; pk.x = cvtpk(t0, t1); pk.y = cvtpk(t2, t3);
        *(uint2*)(h1L[0] + m15 * 128 + ((32 * w + 8 * kgrp) ^ swz)) = pk;
    }
    asm volatile("s_waitcnt lgkmcnt(0)" ::: "memory");
    __builtin_amdgcn_s_barrier();

    float d2f0 = 0.f, d2f1 = 0.f, d2f2 = 0.f, d2f3 = 0.f;

#define LBAR() do { asm volatile("s_waitcnt lgkmcnt(0)" ::: "memory"); \
                    __builtin_amdgcn_s_barrier(); } while (0)
// Phase T: uses emb slot E (tile T+1), refills it with tile T+3.
// Reads bufs[P] = {h1[T], h2[T-1]}, writes bufs[Q] = {h1[T+1], h2[T]}.
#define PHASE(T, E0, E1, E2, E3, TOK, P, Q)                                        \
  {                                                                                \
    bf16x8 bh1a = *(const bf16x8*)(h1L[P] + m15 * 128 + ((kgrp * 16     ) ^ swz)); \
    bf16x8 bh1b = *(const bf16x8*)(h1L[P] + m15 * 128 + ((kgrp * 16 + 64) ^ swz)); \
    bf16x8 bh2a = *(const bf16x8*)(h2L[P] + m15 * 128 + ((kgrp * 16     ) ^ swz)); \
    bf16x8 bh2b = *(const bf16x8*)(h2L[P] + m15 * 128 + ((kgrp * 16 + 64) ^ swz)); \
    /* register-only: W1·emb[T+1], fills the ds_read shadow */                     \
    f32x4 dH = b1c;                                                                \
    dH = MFMA16(aW1[0], E0, dH, 0, 0, 0);                                          \
    dH = MFMA16(aW1[1], E1, dH, 0, 0, 0);                                          \
    dH = MFMA16(aW1[2], E2, dH, 0, 0, 0);                                          \
    dH = MFMA16(aW1[3], E3, dH, 0, 0, 0);                                          \
    {   /* refill this slot with tile T+3 (stays in flight across barrier) */      \
        const ushort* er = emb_bf + (size_t)TOK * 128 + kgrp * 8;                  \
        E0 = *(const bf16x8*)(er);      E1 = *(const bf16x8*)(er + 32);            \
        E2 = *(const bf16x8*)(er + 64); E3 = *(const bf16x8*)(er + 96);            \
    }                                                                              \
    TOK = tokens[b80 + ((T) + 5 < SEQ ? (T) + 5 : SEQ - 1)];                       \
    /* layer2(T): two split chains */                                              \
    f32x4 dC = b2c;                                                                \
    dC = MFMA16(aW2[0], bh1a, dC, 0, 0, 0);                                        \
    dC = MFMA16(aW2[1], bh1b, dC, 0, 0, 0);                                        \
    f32x4 dD = {0.f, 0.f, 0.f, 0.f};                                               \
    dD = MFMA16(aU2[0], bh2a, dD, 0, 0, 0);                                        \
    dD = MFMA16(aU2[1], bh2b, dD, 0, 0, 0);                                        \
    /* layer1(T+1): U1·h1[T] joins dH */                                           \
    f32x4 dB = {0.f, 0.f, 0.f, 0.f};                                               \
    dB = MFMA16(aU1[0], bh1a, dB, 0, 0, 0);                                        \
    dB = MFMA16(aU1[1], bh1b, dB, 0, 0, 0);                                        \
    float n0 = fast_tanh(dH[0] + dB[0]);                                           \
    float n1 = fast_tanh(dH[1] + dB[1]);                                           \
    float n2 = fast_tanh(dH[2] + dB[2]);                                           \
    float n3 = fast_tanh(dH[3] + dB[3]);                                           \
    d2f0 = fast_tanh(dC[0] + dD[0]);                                               \
    d2f1 = fast_tanh(dC[1] + dD[1]);                                               \
    d2f2 = fast_tanh(dC[2] + dD[2]);                                               \
    d2f3 = fast_tanh(dC[3] + dD[3]);                                               \
    {                                                                              \
        uint2 pk; pk.x = cvtpk(n0, n1); pk.y = cvtpk(n2, n3);                      \
        *(uint2*)(h1L[Q] + m15 * 128 + ((32 * w + 8 * kgrp) ^ swz)) = pk;          \
    }                                                                              \
    {                                                                              \
        uint2 pk; pk.x = cvtpk(d2f0, d2f1); pk.y = cvtpk(d2f2, d2f3);              \
        *(uint2*)(h2L[Q] + m15 * 128 + ((32 * w + 8 * kgrp) ^ swz)) = pk;          \
    }                                                                              \
    LBAR();                                                                        \
  }

    for (int t = 0; t < SEQ; t += 2) {
        PHASE(t,     eY0, eY1, eY2, eY3, tokY, 0, 1)   // phase t   (even): P=0
        PHASE(t + 1, eX0, eX1, eX2, eX3, tokX, 1, 0)   // phase t+1 (odd):  P=1
    }
#undef PHASE
#undef LBAR

    // ---- head: out[b] = sigmoid(h2[79] @ Wo + bo) ----
    const f32x4 woc = *(const f32x4*)(Wo + ubase);
    float p = d2f0 * woc[0] + d2f1 * woc[1] + d2f2 * woc[2] + d2f3 * woc[3];
    p += __shfl_xor(p, 16, 64);
    p += __shfl_xor(p, 32, 64);
    if (lane < 16) headp[w][lane] = p;
    __syncthreads();
    if (threadIdx.x < 16) {
        const float z = headp[0][threadIdx.x] + headp[1][threadIdx.x]
                      + headp[2][threadIdx.x] + headp[3][threadIdx.x] + bo[0];
        const float e = __builtin_amdgcn_exp2f(-z * 1.4426950408889634f);
        out[wg * 16 + threadIdx.x] = __builtin_amdgcn_rcpf(1.0f + e);
    }
}

extern "C" void kernel_launch(void* const* d_in, const int* in_sizes, int n_in,
                              void* d_out, int out_size, void* d_ws, size_t ws_size,
                              hipStream_t stream) {
    const int*   tokens = (const int*)  d_in[0];
    const float* emb    = (const float*)d_in[1];
    const float* W1     = (const float*)d_in[2];
    const float* U1     = (const float*)d_in[3];
    const float* b1     = (const float*)d_in[4];
    const float* W2     = (const float*)d_in[5];
    const float* U2     = (const float*)d_in[6];
    const float* b2     = (const float*)d_in[7];
    const float* Wo     = (const float*)d_in[8];
    const float* bo     = (const float*)d_in[9];
    float* out = (float*)d_out;
    char*  ws  = (char*)d_ws;

    prep_kernel<<<640, 256, 0, stream>>>(emb, W1, U1, W2, U2, ws);
    rnn_kernel<<<NWG, 256, 0, stream>>>(tokens, b1, b2, Wo, bo, out, ws);
}